// Round 1
// baseline (770.860 us; speedup 1.0000x reference)
//
#include <hip/hip_runtime.h>

typedef unsigned int u32;

#define BB 64
#define HH 512
#define WW 512
#define HWP 262144            // 512*512
#define WPI 8192              // words per image (512*16)
#define NBV 8192              // value histogram bins
#define NBS 4096              // score histogram bins
#define EPSF 1e-8f
#define NBGK 78643            // int(0.3 * 512*512)
#define CAND_CAP 4096
#define SEL_CAP 128
#define PN 20

// prm fields per image:
// 0 nfg, 1 deg, 2 Bf, 3 rf, 4 Bb, 5 rb, 6 ubf, 7 ibf, 8 ubb, 9 ibb,
// 10 sbf, 12 needf, 13 sbb, 15 needb, 16 kf, 17 kb

__device__ __forceinline__ int vbucket(float vb){
    int b = (int)(vb * 8192.0f);
    b = b < 0 ? 0 : b;
    return b > (NBV-1) ? (NBV-1) : b;
}
__device__ __forceinline__ int sbucket(float s){
    float a = (s + 24.0f) * (4096.0f / 44.0f);
    a = fmaxf(a, 0.0f);
    int b = (int)a;
    return b > (NBS-1) ? (NBS-1) : b;
}
__device__ __forceinline__ u32 flipf(float s){
    u32 u = __float_as_uint(s);
    u32 m = (u & 0x80000000u) ? 0xFFFFFFFFu : 0x80000000u;
    return u ^ m;
}

// K1: roi0 bits, bg value hist, per-image min/max bits, out = -255
__global__ __launch_bounds__(256) void k_prep(const float* __restrict__ x,
        const float* __restrict__ thr, u32* __restrict__ roi0,
        u32* __restrict__ ghist_bg, u32* __restrict__ minb, u32* __restrict__ maxb,
        int* __restrict__ out)
{
    __shared__ u32 hist[NBV];
    for (int i = threadIdx.x; i < NBV; i += 256) hist[i] = 0u;
    __syncthreads();
    int img = blockIdx.x >> 5;
    int blk = blockIdx.x & 31;
    int pixBase = blk * 8192 + threadIdx.x * 32;
    const float* camp = x + (size_t)img * HWP + pixBase;
    int* outp = out + (size_t)img * HWP + pixBase;
    float t = thr[img];
    t = (t == 0.0f) ? 1.0f : ((t == 255.0f) ? 254.0f : t);
    u32 word = 0u;
    u32 mn = 0xFFFFFFFFu, mx = 0u;
    const float4* c4 = (const float4*)camp;
    int4* o4 = (int4*)outp;
    #pragma unroll
    for (int j = 0; j < 8; j++){
        float4 v4 = c4[j];
        float vv[4] = {v4.x, v4.y, v4.z, v4.w};
        #pragma unroll
        for (int c = 0; c < 4; c++){
            float v = vv[c];
            u32 ub = __float_as_uint(v);
            mn = mn < ub ? mn : ub;
            mx = mx > ub ? mx : ub;
            if (floorf(v * 255.0f) > t) word |= (1u << (j*4+c));
            float vb = v + EPSF;
            atomicAdd(&hist[vbucket(vb)], 1u);
        }
        o4[j] = make_int4(-255,-255,-255,-255);
    }
    roi0[(size_t)img * WPI + blk*256 + threadIdx.x] = word;
    for (int o = 32; o >= 1; o >>= 1){
        u32 m2 = __shfl_down(mn, o); mn = mn < m2 ? mn : m2;
        u32 m3 = __shfl_down(mx, o); mx = mx > m3 ? mx : m3;
    }
    if ((threadIdx.x & 63) == 0){
        atomicMin(&minb[img], mn);
        atomicMax(&maxb[img], mx);
    }
    __syncthreads();
    for (int i = threadIdx.x; i < NBV; i += 256){
        u32 h = hist[i];
        if (h) atomicAdd(&ghist_bg[(size_t)img*NBV + i], h);
    }
}

// K2: horizontal 11-wide binary erosion (bitwise AND of shifts, borders = identity)
__global__ __launch_bounds__(256) void k_erodeh(const u32* __restrict__ roi0, u32* __restrict__ roiH)
{
    int idx = blockIdx.x * 256 + threadIdx.x;
    if (idx >= BB * WPI) return;
    int wr = idx & 15;
    u32 cur = roi0[idx];
    u32 left  = (wr > 0)  ? roi0[idx-1] : 0xFFFFFFFFu;
    u32 right = (wr < 15) ? roi0[idx+1] : 0xFFFFFFFFu;
    u32 res = cur;
    #pragma unroll
    for (int d = 1; d <= 5; d++){
        res &= (cur >> d) | (right << (32 - d));
        res &= (cur << d) | (left  >> (32 - d));
    }
    roiH[idx] = res;
}

// K3: vertical 11 erosion + popcount -> roiSum
__global__ __launch_bounds__(256) void k_erodev(const u32* __restrict__ roiH, u32* __restrict__ roiE,
        u32* __restrict__ roiSum)
{
    int idx = blockIdx.x * 256 + threadIdx.x;
    if (idx >= BB * WPI) return;
    int img = idx >> 13;
    int wi = idx & (WPI-1);
    int r = wi >> 4;
    const u32* basep = roiH + (size_t)img * WPI;
    u32 res = 0xFFFFFFFFu;
    #pragma unroll
    for (int d = -5; d <= 5; d++){
        int rr = r + d;
        if (rr >= 0 && rr < HH) res &= basep[wi + d*16];
    }
    roiE[idx] = res;
    u32 c = __popc(res);
    for (int o = 32; o >= 1; o >>= 1) c += __shfl_down(c, o);
    if ((threadIdx.x & 63) == 0) atomicAdd(&roiSum[img], c);
}

// K4: fg value histogram over eroded-ROI pixels
__global__ __launch_bounds__(256) void k_fghist(const float* __restrict__ x, const u32* __restrict__ roiE,
        u32* __restrict__ ghist_fg)
{
    __shared__ u32 hist[NBV];
    for (int i = threadIdx.x; i < NBV; i += 256) hist[i] = 0u;
    __syncthreads();
    int img = blockIdx.x >> 5;
    int blk = blockIdx.x & 31;
    u32 w = roiE[(size_t)img*WPI + blk*256 + threadIdx.x];
    if (w){
        const float* camp = x + (size_t)img * HWP + blk*8192 + threadIdx.x*32;
        const float4* c4 = (const float4*)camp;
        #pragma unroll
        for (int j = 0; j < 8; j++){
            if ((w >> (j*4)) & 0xFu){
                float4 v4 = c4[j];
                float vv[4] = {v4.x, v4.y, v4.z, v4.w};
                #pragma unroll
                for (int c = 0; c < 4; c++){
                    if ((w >> (j*4+c)) & 1u){
                        atomicAdd(&hist[vbucket(vv[c] + EPSF)], 1u);
                    }
                }
            }
        }
    }
    __syncthreads();
    for (int i = threadIdx.x; i < NBV; i += 256){
        u32 h = hist[i];
        if (h) atomicAdd(&ghist_fg[(size_t)img*NBV + i], h);
    }
}

// K5: per-image scan of value hists -> boundary bucket + in-bucket rank
__global__ __launch_bounds__(256) void k_bound1(const u32* __restrict__ ghf, const u32* __restrict__ ghb,
        const u32* __restrict__ minb, const u32* __restrict__ maxb, const u32* __restrict__ roiSum,
        int* __restrict__ prm)
{
    int b = blockIdx.x, t = threadIdx.x;
    __shared__ int partial[256];
    __shared__ int res[2];
    int deg = (minb[b] == maxb[b]) ? 1 : 0;
    int nfg = (int)floorf(0.3f * (float)(int)roiSum[b]);
    int Bf = -1, rf = 0, Bb = -1, rb = 0;
    if (!deg && nfg > 0){
        const u32* hh = ghf + (size_t)b * NBV;
        int s = 0;
        for (int i = 0; i < 32; i++) s += (int)hh[NBV-1 - (t*32+i)];
        partial[t] = s;
        __syncthreads();
        if (t == 0){
            int cum = 0, q = 0;
            for (; q < 256; q++){ if (cum + partial[q] >= nfg) break; cum += partial[q]; }
            for (int i = 0; i < 32; i++){
                int bkt = NBV-1 - (q*32+i);
                int h = (int)hh[bkt];
                if (cum + h >= nfg){ res[0] = bkt; res[1] = nfg - cum; break; }
                cum += h;
            }
        }
        __syncthreads();
        Bf = res[0]; rf = res[1];
        __syncthreads();
    }
    if (!deg){
        const u32* hh = ghb + (size_t)b * NBV;
        int s = 0;
        for (int i = 0; i < 32; i++) s += (int)hh[t*32+i];
        partial[t] = s;
        __syncthreads();
        if (t == 0){
            int cum = 0, q = 0;
            for (; q < 256; q++){ if (cum + partial[q] >= NBGK) break; cum += partial[q]; }
            for (int i = 0; i < 32; i++){
                int bkt = q*32+i;
                int h = (int)hh[bkt];
                if (cum + h >= NBGK){ res[0] = bkt; res[1] = NBGK - cum; break; }
                cum += h;
            }
        }
        __syncthreads();
        Bb = res[0]; rb = res[1];
    }
    if (t == 0){
        int* p = prm + b * PN;
        p[0] = nfg; p[1] = deg; p[2] = Bf; p[3] = rf; p[4] = Bb; p[5] = rb;
    }
}

// K6: collect boundary-bucket candidates (value bits, pixel idx)
__global__ __launch_bounds__(256) void k_collect1(const float* __restrict__ x, const u32* __restrict__ roiE,
        const int* __restrict__ prm,
        uint2* __restrict__ candF, u32* __restrict__ cntF,
        uint2* __restrict__ candB, u32* __restrict__ cntB)
{
    int img = blockIdx.x >> 5;
    int blk = blockIdx.x & 31;
    int Bf = prm[img*PN + 2];
    int Bb = prm[img*PN + 4];
    u32 w = roiE[(size_t)img*WPI + blk*256 + threadIdx.x];
    int pixBase = blk*8192 + threadIdx.x*32;
    const float4* c4 = (const float4*)(x + (size_t)img * HWP + pixBase);
    #pragma unroll
    for (int j = 0; j < 8; j++){
        float4 v4 = c4[j];
        float vv[4] = {v4.x, v4.y, v4.z, v4.w};
        #pragma unroll
        for (int c = 0; c < 4; c++){
            float vb = vv[c] + EPSF;
            int bkt = vbucket(vb);
            int pix = pixBase + j*4 + c;
            if (bkt == Bb){
                u32 q = atomicAdd(&cntB[img], 1u);
                if (q < CAND_CAP) candB[(size_t)img*CAND_CAP + q] = make_uint2(__float_as_uint(vb), (u32)pix);
            }
            if (bkt == Bf && ((w >> (j*4+c)) & 1u)){
                u32 q = atomicAdd(&cntF[img], 1u);
                if (q < CAND_CAP) candF[(size_t)img*CAND_CAP + q] = make_uint2(__float_as_uint(vb), (u32)pix);
            }
        }
    }
}

// K7: resolve exact (bits, idx) threshold within boundary bucket
__global__ __launch_bounds__(256) void k_resolve1(const uint2* __restrict__ candF, const u32* __restrict__ cntF,
        const uint2* __restrict__ candB, const u32* __restrict__ cntB, int* __restrict__ prm)
{
    int b = blockIdx.x, t = threadIdx.x;
    __shared__ uint2 c[CAND_CAP];
    int rf = prm[b*PN + 3];
    if (rf > 0){
        int m = (int)cntF[b]; m = m < CAND_CAP ? m : CAND_CAP;
        for (int i = t; i < m; i += 256) c[i] = candF[(size_t)b*CAND_CAP + i];
        __syncthreads();
        for (int i = t; i < m; i += 256){
            u32 ki = c[i].x, xi = c[i].y;
            int r = 0;
            for (int j = 0; j < m; j++){
                u32 kj = c[j].x, xj = c[j].y;
                r += (kj > ki) || (kj == ki && xj < xi);
            }
            if (r == rf - 1){ prm[b*PN + 6] = (int)ki; prm[b*PN + 7] = (int)xi; }
        }
    } else if (t == 0){
        prm[b*PN + 6] = (int)0xFFFFFFFFu; prm[b*PN + 7] = -1;
    }
    __syncthreads();
    int rb = prm[b*PN + 5];
    if (rb > 0){
        int m = (int)cntB[b]; m = m < CAND_CAP ? m : CAND_CAP;
        for (int i = t; i < m; i += 256) c[i] = candB[(size_t)b*CAND_CAP + i];
        __syncthreads();
        for (int i = t; i < m; i += 256){
            u32 ki = c[i].x, xi = c[i].y;
            int r = 0;
            for (int j = 0; j < m; j++){
                u32 kj = c[j].x, xj = c[j].y;
                r += (kj < ki) || (kj == ki && xj < xi);
            }
            if (r == rb - 1){ prm[b*PN + 8] = (int)ki; prm[b*PN + 9] = (int)xi; }
        }
    } else if (t == 0){
        prm[b*PN + 8] = 0; prm[b*PN + 9] = -1;
    }
}

// K8: score histograms for masked fg/bg pixels
__global__ __launch_bounds__(256) void k_shist(const float* __restrict__ x, const u32* __restrict__ roiE,
        const float* __restrict__ ufg, const float* __restrict__ ubg, const int* __restrict__ prm,
        u32* __restrict__ shfG, u32* __restrict__ shbG)
{
    __shared__ u32 hf[NBS];
    __shared__ u32 hb[NBS];
    for (int i = threadIdx.x; i < NBS; i += 256){ hf[i] = 0u; hb[i] = 0u; }
    __syncthreads();
    int img = blockIdx.x >> 5;
    int blk = blockIdx.x & 31;
    const int* p = prm + img*PN;
    u32 ubf = (u32)p[6]; int ibf = p[7];
    u32 ubb = (u32)p[8]; int ibb = p[9];
    u32 w = roiE[(size_t)img*WPI + blk*256 + threadIdx.x];
    int pixBase = blk*8192 + threadIdx.x*32;
    size_t gbase = (size_t)img * HWP + pixBase;
    const float4* c4 = (const float4*)(x + gbase);
    #pragma unroll
    for (int j = 0; j < 8; j++){
        float4 v4 = c4[j];
        float vv[4] = {v4.x, v4.y, v4.z, v4.w};
        #pragma unroll
        for (int c = 0; c < 4; c++){
            float vb = vv[c] + EPSF;
            u32 bu = __float_as_uint(vb);
            int pix = pixBase + j*4 + c;
            if (((w >> (j*4+c)) & 1u) && (bu > ubf || (bu == ubf && pix <= ibf))){
                float u = ufg[gbase + (j*4+c)];
                float s = logf(vb) - logf(-logf(u));
                atomicAdd(&hf[sbucket(s)], 1u);
            }
            if (bu < ubb || (bu == ubb && pix <= ibb)){
                float u = ubg[gbase + (j*4+c)];
                float pb = fmaxf(1.0f - vb, 0.0f) + EPSF;
                float s = logf(pb) - logf(-logf(u));
                atomicAdd(&hb[sbucket(s)], 1u);
            }
        }
    }
    __syncthreads();
    for (int i = threadIdx.x; i < NBS; i += 256){
        u32 h = hf[i]; if (h) atomicAdd(&shfG[(size_t)img*NBS + i], h);
        h = hb[i];     if (h) atomicAdd(&shbG[(size_t)img*NBS + i], h);
    }
}

// K8b: scan score hists -> boundary bucket + needed-from-boundary counts
__global__ __launch_bounds__(256) void k_bound2(const u32* __restrict__ shfG, const u32* __restrict__ shbG,
        int* __restrict__ prm)
{
    int b = blockIdx.x, t = threadIdx.x;
    __shared__ int partial[256];
    __shared__ int res[2];
    int* p = prm + b*PN;
    int nfg = p[0], deg = p[1];
    int kf = (deg || nfg <= 0) ? 0 : (nfg < 100 ? nfg : 100);
    int kb = deg ? 0 : 100;
    int sbf = 0x7FFFFFFF, needf = 0, sbb = 0x7FFFFFFF, needb = 0;
    if (kf > 0){
        const u32* hh = shfG + (size_t)b * NBS;
        int s = 0;
        for (int i = 0; i < 16; i++) s += (int)hh[NBS-1 - (t*16+i)];
        partial[t] = s;
        __syncthreads();
        if (t == 0){
            int cum = 0, q = 0;
            for (; q < 256; q++){ if (cum + partial[q] >= kf) break; cum += partial[q]; }
            for (int i = 0; i < 16; i++){
                int bkt = NBS-1 - (q*16+i);
                int h = (int)hh[bkt];
                if (cum + h >= kf){ res[0] = bkt; res[1] = kf - cum; break; }
                cum += h;
            }
        }
        __syncthreads();
        sbf = res[0]; needf = res[1];
        __syncthreads();
    }
    if (kb > 0){
        const u32* hh = shbG + (size_t)b * NBS;
        int s = 0;
        for (int i = 0; i < 16; i++) s += (int)hh[NBS-1 - (t*16+i)];
        partial[t] = s;
        __syncthreads();
        if (t == 0){
            int cum = 0, q = 0;
            for (; q < 256; q++){ if (cum + partial[q] >= kb) break; cum += partial[q]; }
            for (int i = 0; i < 16; i++){
                int bkt = NBS-1 - (q*16+i);
                int h = (int)hh[bkt];
                if (cum + h >= kb){ res[0] = bkt; res[1] = kb - cum; break; }
                cum += h;
            }
        }
        __syncthreads();
        sbb = res[0]; needb = res[1];
    }
    if (t == 0){
        p[10] = sbf; p[12] = needf; p[13] = sbb; p[15] = needb; p[16] = kf; p[17] = kb;
    }
}

// K9: collect score winners (above boundary bucket) + boundary candidates
__global__ __launch_bounds__(256) void k_collect2(const float* __restrict__ x, const u32* __restrict__ roiE,
        const float* __restrict__ ufg, const float* __restrict__ ubg, const int* __restrict__ prm,
        uint2* __restrict__ selF, u32* __restrict__ cntSelF, uint2* __restrict__ scandF, u32* __restrict__ cntScF,
        uint2* __restrict__ selB, u32* __restrict__ cntSelB, uint2* __restrict__ scandB, u32* __restrict__ cntScB)
{
    int img = blockIdx.x >> 5;
    int blk = blockIdx.x & 31;
    const int* p = prm + img*PN;
    u32 ubf = (u32)p[6]; int ibf = p[7];
    u32 ubb = (u32)p[8]; int ibb = p[9];
    int sbf = p[10], sbb = p[13];
    u32 w = roiE[(size_t)img*WPI + blk*256 + threadIdx.x];
    int pixBase = blk*8192 + threadIdx.x*32;
    size_t gbase = (size_t)img * HWP + pixBase;
    const float4* c4 = (const float4*)(x + gbase);
    #pragma unroll
    for (int j = 0; j < 8; j++){
        float4 v4 = c4[j];
        float vv[4] = {v4.x, v4.y, v4.z, v4.w};
        #pragma unroll
        for (int c = 0; c < 4; c++){
            float vb = vv[c] + EPSF;
            u32 bu = __float_as_uint(vb);
            int pix = pixBase + j*4 + c;
            if (((w >> (j*4+c)) & 1u) && (bu > ubf || (bu == ubf && pix <= ibf))){
                float u = ufg[gbase + (j*4+c)];
                float s = logf(vb) - logf(-logf(u));
                int sb = sbucket(s);
                if (sb > sbf){
                    u32 q = atomicAdd(&cntSelF[img], 1u);
                    if (q < SEL_CAP) selF[(size_t)img*SEL_CAP + q] = make_uint2(flipf(s), (u32)pix);
                } else if (sb == sbf){
                    u32 q = atomicAdd(&cntScF[img], 1u);
                    if (q < CAND_CAP) scandF[(size_t)img*CAND_CAP + q] = make_uint2(flipf(s), (u32)pix);
                }
            }
            if (bu < ubb || (bu == ubb && pix <= ibb)){
                float u = ubg[gbase + (j*4+c)];
                float pb = fmaxf(1.0f - vb, 0.0f) + EPSF;
                float s = logf(pb) - logf(-logf(u));
                int sb = sbucket(s);
                if (sb > sbb){
                    u32 q = atomicAdd(&cntSelB[img], 1u);
                    if (q < SEL_CAP) selB[(size_t)img*SEL_CAP + q] = make_uint2(flipf(s), (u32)pix);
                } else if (sb == sbb){
                    u32 q = atomicAdd(&cntScB[img], 1u);
                    if (q < CAND_CAP) scandB[(size_t)img*CAND_CAP + q] = make_uint2(flipf(s), (u32)pix);
                }
            }
        }
    }
}

// K11: finalize top-k seed sets + 3x3 dilation paint with overlap cancel
__global__ __launch_bounds__(256) void k_final(
        const uint2* __restrict__ selF, const u32* __restrict__ cntSelF,
        const uint2* __restrict__ scandF, const u32* __restrict__ cntScF,
        const uint2* __restrict__ selB, const u32* __restrict__ cntSelB,
        const uint2* __restrict__ scandB, const u32* __restrict__ cntScB,
        const int* __restrict__ prm, int* __restrict__ out)
{
    int b = blockIdx.x, t = threadIdx.x;
    __shared__ uint2 c[CAND_CAP];
    __shared__ int seedF[SEL_CAP];
    __shared__ int seedB[SEL_CAP];
    __shared__ int nF, nB;
    const int* p = prm + b*PN;
    int needf = p[12], needb = p[15];

    // FG
    int c0 = (int)cntSelF[b]; c0 = c0 < SEL_CAP ? c0 : SEL_CAP;
    for (int i = t; i < c0; i += 256) seedF[i] = (int)selF[(size_t)b*SEL_CAP + i].y;
    int m = (int)cntScF[b]; m = m < CAND_CAP ? m : CAND_CAP;
    for (int i = t; i < m; i += 256) c[i] = scandF[(size_t)b*CAND_CAP + i];
    if (t == 0){ nF = c0; nB = 0; }
    __syncthreads();
    for (int i = t; i < m; i += 256){
        u32 ki = c[i].x, xi = c[i].y;
        int r = 0;
        for (int j = 0; j < m; j++){
            u32 kj = c[j].x, xj = c[j].y;
            r += (kj > ki) || (kj == ki && xj < xi);
        }
        if (r < needf){
            int q = atomicAdd(&nF, 1);
            if (q < SEL_CAP) seedF[q] = (int)xi;
        }
    }
    __syncthreads();
    int fN = nF; fN = fN < SEL_CAP ? fN : SEL_CAP;
    __syncthreads();

    // BG
    int c0b = (int)cntSelB[b]; c0b = c0b < SEL_CAP ? c0b : SEL_CAP;
    for (int i = t; i < c0b; i += 256) seedB[i] = (int)selB[(size_t)b*SEL_CAP + i].y;
    int mb = (int)cntScB[b]; mb = mb < CAND_CAP ? mb : CAND_CAP;
    for (int i = t; i < mb; i += 256) c[i] = scandB[(size_t)b*CAND_CAP + i];
    if (t == 0) nB = c0b;
    __syncthreads();
    for (int i = t; i < mb; i += 256){
        u32 ki = c[i].x, xi = c[i].y;
        int r = 0;
        for (int j = 0; j < mb; j++){
            u32 kj = c[j].x, xj = c[j].y;
            r += (kj > ki) || (kj == ki && xj < xi);
        }
        if (r < needb){
            int q = atomicAdd(&nB, 1);
            if (q < SEL_CAP) seedB[q] = (int)xi;
        }
    }
    __syncthreads();
    int bN = nB; bN = bN < SEL_CAP ? bN : SEL_CAP;
    __syncthreads();

    int* outp = out + (size_t)b * HWP;
    // paint fg = 1 where dilated-fg and not dilated-bg
    for (int task = t; task < fN * 9; task += 256){
        int s = seedF[task / 9];
        int o = task % 9;
        int y = (s >> 9) + (o / 3) - 1;
        int xx = (s & 511) + (o % 3) - 1;
        if (y < 0 || y >= HH || xx < 0 || xx >= WW) continue;
        bool conf = false;
        for (int j = 0; j < bN; j++){
            int sb2 = seedB[j];
            int dy = y - (sb2 >> 9); if (dy < 0) dy = -dy;
            int dx = xx - (sb2 & 511); if (dx < 0) dx = -dx;
            if (dy <= 1 && dx <= 1){ conf = true; break; }
        }
        if (!conf) outp[y * WW + xx] = 1;
    }
    // paint bg = 0 where dilated-bg and not dilated-fg
    for (int task = t; task < bN * 9; task += 256){
        int s = seedB[task / 9];
        int o = task % 9;
        int y = (s >> 9) + (o / 3) - 1;
        int xx = (s & 511) + (o % 3) - 1;
        if (y < 0 || y >= HH || xx < 0 || xx >= WW) continue;
        bool conf = false;
        for (int j = 0; j < fN; j++){
            int sf2 = seedF[j];
            int dy = y - (sf2 >> 9); if (dy < 0) dy = -dy;
            int dx = xx - (sf2 & 511); if (dx < 0) dx = -dx;
            if (dy <= 1 && dx <= 1){ conf = true; break; }
        }
        if (!conf) outp[y * WW + xx] = 0;
    }
}

extern "C" void kernel_launch(void* const* d_in, const int* in_sizes, int n_in,
                              void* d_out, int out_size, void* d_ws, size_t ws_size,
                              hipStream_t stream)
{
    (void)in_sizes; (void)n_in; (void)out_size; (void)ws_size;
    const float* x   = (const float*)d_in[0];
    const float* thr = (const float*)d_in[1];
    const float* ufg = (const float*)d_in[2];
    const float* ubg = (const float*)d_in[3];
    int* out = (int*)d_out;
    char* ws = (char*)d_ws;

    size_t off = 0;
    auto carve = [&](size_t bytes) -> char* {
        char* ptr = ws + off;
        off = (off + bytes + 255) & ~(size_t)255;
        return ptr;
    };
    u32* ghist_bg = (u32*)carve((size_t)BB*NBV*4);
    u32* ghist_fg = (u32*)carve((size_t)BB*NBV*4);
    u32* shf      = (u32*)carve((size_t)BB*NBS*4);
    u32* shb      = (u32*)carve((size_t)BB*NBS*4);
    u32* cnts     = (u32*)carve((size_t)6*BB*4);
    u32* maxb     = (u32*)carve((size_t)BB*4);
    u32* roiSum   = (u32*)carve((size_t)BB*4);
    size_t zero_bytes = off;
    u32* minb     = (u32*)carve((size_t)BB*4);
    size_t minb_off = (size_t)((char*)minb - ws);
    u32* roi0     = (u32*)carve((size_t)BB*WPI*4);
    u32* roiH     = (u32*)carve((size_t)BB*WPI*4);
    u32* roiE     = (u32*)carve((size_t)BB*WPI*4);
    int* prm      = (int*)carve((size_t)BB*PN*4);
    uint2* candF  = (uint2*)carve((size_t)BB*CAND_CAP*8);
    uint2* candB  = (uint2*)carve((size_t)BB*CAND_CAP*8);
    uint2* scandF = (uint2*)carve((size_t)BB*CAND_CAP*8);
    uint2* scandB = (uint2*)carve((size_t)BB*CAND_CAP*8);
    uint2* selF   = (uint2*)carve((size_t)BB*SEL_CAP*8);
    uint2* selB   = (uint2*)carve((size_t)BB*SEL_CAP*8);
    u32* cntF = cnts, *cntB = cnts + BB, *cntSelF = cnts + 2*BB,
       *cntScF = cnts + 3*BB, *cntSelB = cnts + 4*BB, *cntScB = cnts + 5*BB;

    hipMemsetAsync(ws, 0, zero_bytes, stream);
    hipMemsetAsync(ws + minb_off, 0xFF, (size_t)BB*4, stream);

    k_prep   <<<2048, 256, 0, stream>>>(x, thr, roi0, ghist_bg, minb, maxb, out);
    k_erodeh <<<2048, 256, 0, stream>>>(roi0, roiH);
    k_erodev <<<2048, 256, 0, stream>>>(roiH, roiE, roiSum);
    k_fghist <<<2048, 256, 0, stream>>>(x, roiE, ghist_fg);
    k_bound1 <<<64,   256, 0, stream>>>(ghist_fg, ghist_bg, minb, maxb, roiSum, prm);
    k_collect1<<<2048,256, 0, stream>>>(x, roiE, prm, candF, cntF, candB, cntB);
    k_resolve1<<<64,  256, 0, stream>>>(candF, cntF, candB, cntB, prm);
    k_shist  <<<2048, 256, 0, stream>>>(x, roiE, ufg, ubg, prm, shf, shb);
    k_bound2 <<<64,   256, 0, stream>>>(shf, shb, prm);
    k_collect2<<<2048,256, 0, stream>>>(x, roiE, ufg, ubg, prm,
                                        selF, cntSelF, scandF, cntScF,
                                        selB, cntSelB, scandB, cntScB);
    k_final  <<<64,   256, 0, stream>>>(selF, cntSelF, scandF, cntScF,
                                        selB, cntSelB, scandB, cntScB, prm, out);
}

// Round 2
// 495.941 us; speedup vs baseline: 1.5543x; 1.5543x over previous
//
#include <hip/hip_runtime.h>

typedef unsigned int u32;

#define BB 64
#define HH 512
#define WW 512
#define HWP 262144            // 512*512
#define WPI 8192              // words per image (512*16)
#define NBV 8192              // value histogram bins
#define NBS 4096              // score histogram bins
#define EPSF 1e-8f
#define NBGK 78643            // int(0.3 * 512*512)
#define CAND_CAP 4096
#define SEL_CAP 128
#define PN 20

// prm fields per image:
// 0 nfg, 1 deg, 2 Bf, 3 rf, 4 Bb, 5 rb, 6 ubf, 7 ibf, 8 ubb, 9 ibb,
// 10 sbf, 12 needf, 13 sbb, 15 needb, 16 kf, 17 kb

__device__ __forceinline__ int vbucket(float vb){
    int b = (int)(vb * 8192.0f);
    b = b < 0 ? 0 : b;
    return b > (NBV-1) ? (NBV-1) : b;
}
__device__ __forceinline__ int sbucket(float s){
    float a = (s + 24.0f) * (4096.0f / 44.0f);
    a = fmaxf(a, 0.0f);
    int b = (int)a;
    return b > (NBS-1) ? (NBS-1) : b;
}
__device__ __forceinline__ u32 flipf(float s){
    u32 u = __float_as_uint(s);
    u32 m = (u & 0x80000000u) ? 0xFFFFFFFFu : 0x80000000u;
    return u ^ m;
}

// Interleaved mapping: block = (img, blk of 8192 px). Iter k, thread t handles
// float4 index blk*2048 + k*256 + t  (pixels blk*8192 + k*1024 + t*4 .. +3).
// -> every wave vector op touches 64 lanes x 16B = 1KB contiguous.

// K1: roi0 bits, bg value hist, per-image min/max bits, out = -255
__global__ __launch_bounds__(256) void k_prep(const float* __restrict__ x,
        const float* __restrict__ thr, u32* __restrict__ roi0,
        u32* __restrict__ ghist_bg, u32* __restrict__ minb, u32* __restrict__ maxb,
        int* __restrict__ out)
{
    __shared__ u32 hist[NBV];
    __shared__ u32 words[256];
    for (int i = threadIdx.x; i < NBV; i += 256) hist[i] = 0u;
    words[threadIdx.x] = 0u;
    __syncthreads();
    int img = blockIdx.x >> 5;
    int blk = blockIdx.x & 31;
    int t = threadIdx.x;
    size_t base4 = (size_t)img * (HWP/4) + (size_t)blk * 2048;
    const float4* c4 = (const float4*)x + base4;
    int4* o4 = (int4*)out + base4;
    float th = thr[img];
    th = (th == 0.0f) ? 1.0f : ((th == 255.0f) ? 254.0f : th);
    u32 mn = 0xFFFFFFFFu, mx = 0u;
    #pragma unroll
    for (int k = 0; k < 8; k++){
        float4 v4 = c4[k*256 + t];
        float vv[4] = {v4.x, v4.y, v4.z, v4.w};
        u32 nib = 0u;
        #pragma unroll
        for (int c = 0; c < 4; c++){
            float v = vv[c];
            u32 ub = __float_as_uint(v);
            mn = mn < ub ? mn : ub;
            mx = mx > ub ? mx : ub;
            if (floorf(v * 255.0f) > th) nib |= (1u << c);
            atomicAdd(&hist[vbucket(v + EPSF)], 1u);
        }
        if (nib) atomicOr(&words[k*32 + (t>>3)], nib << ((t&7)*4));
        o4[k*256 + t] = make_int4(-255,-255,-255,-255);
    }
    for (int o = 32; o >= 1; o >>= 1){
        u32 m2 = __shfl_down(mn, o); mn = mn < m2 ? mn : m2;
        u32 m3 = __shfl_down(mx, o); mx = mx > m3 ? mx : m3;
    }
    if ((t & 63) == 0){
        atomicMin(&minb[img], mn);
        atomicMax(&maxb[img], mx);
    }
    __syncthreads();
    roi0[(size_t)img * WPI + blk*256 + t] = words[t];
    for (int i = t; i < NBV; i += 256){
        u32 h = hist[i];
        if (h) atomicAdd(&ghist_bg[(size_t)img*NBV + i], h);
    }
}

// K2: fused 11x11 binary erosion (h then v) in LDS, one block per image,
// + popcount -> roiSum (plain store, no global atomics)
__global__ __launch_bounds__(256) void k_erode(const u32* __restrict__ roi0,
        u32* __restrict__ roiE, u32* __restrict__ roiSum)
{
    __shared__ u32 A[WPI];   // 32KB
    __shared__ u32 Bm[WPI];  // 32KB
    int img = blockIdx.x, t = threadIdx.x;
    const u32* src = roi0 + (size_t)img * WPI;
    for (int i = t; i < WPI; i += 256) A[i] = src[i];
    __syncthreads();
    for (int i = t; i < WPI; i += 256){
        int wr = i & 15;
        u32 cur = A[i];
        u32 left  = (wr > 0)  ? A[i-1] : 0xFFFFFFFFu;
        u32 right = (wr < 15) ? A[i+1] : 0xFFFFFFFFu;
        u32 res = cur;
        #pragma unroll
        for (int d = 1; d <= 5; d++){
            res &= (cur >> d) | (right << (32 - d));
            res &= (cur << d) | (left  >> (32 - d));
        }
        Bm[i] = res;
    }
    __syncthreads();
    if (t == 0) A[0] = 0u;
    __syncthreads();
    u32 cnt = 0u;
    u32* dst = roiE + (size_t)img * WPI;
    for (int i = t; i < WPI; i += 256){
        int r = i >> 4;
        u32 res = 0xFFFFFFFFu;
        #pragma unroll
        for (int d = -5; d <= 5; d++){
            int rr = r + d;
            if (rr >= 0 && rr < HH) res &= Bm[i + d*16];
        }
        dst[i] = res;
        cnt += __popc(res);
    }
    for (int o = 32; o >= 1; o >>= 1) cnt += __shfl_down(cnt, o);
    if ((t & 63) == 0) atomicAdd(&A[0], cnt);
    __syncthreads();
    if (t == 0) roiSum[img] = A[0];
}

// K4: fg value histogram over eroded-ROI pixels (interleaved, LDS roi words)
__global__ __launch_bounds__(256) void k_fghist(const float* __restrict__ x, const u32* __restrict__ roiE,
        u32* __restrict__ ghist_fg)
{
    __shared__ u32 hist[NBV];
    __shared__ u32 words[256];
    for (int i = threadIdx.x; i < NBV; i += 256) hist[i] = 0u;
    int img = blockIdx.x >> 5;
    int blk = blockIdx.x & 31;
    int t = threadIdx.x;
    words[t] = roiE[(size_t)img*WPI + blk*256 + t];
    __syncthreads();
    const float4* c4 = (const float4*)x + (size_t)img * (HWP/4) + (size_t)blk * 2048;
    #pragma unroll
    for (int k = 0; k < 8; k++){
        u32 nib = (words[k*32 + (t>>3)] >> ((t&7)*4)) & 0xFu;
        if (nib){
            float4 v4 = c4[k*256 + t];
            float vv[4] = {v4.x, v4.y, v4.z, v4.w};
            #pragma unroll
            for (int c = 0; c < 4; c++){
                if ((nib >> c) & 1u) atomicAdd(&hist[vbucket(vv[c] + EPSF)], 1u);
            }
        }
    }
    __syncthreads();
    for (int i = t; i < NBV; i += 256){
        u32 h = hist[i];
        if (h) atomicAdd(&ghist_fg[(size_t)img*NBV + i], h);
    }
}

// K5: per-image scan of value hists -> boundary bucket + in-bucket rank
__global__ __launch_bounds__(256) void k_bound1(const u32* __restrict__ ghf, const u32* __restrict__ ghb,
        const u32* __restrict__ minb, const u32* __restrict__ maxb, const u32* __restrict__ roiSum,
        int* __restrict__ prm)
{
    int b = blockIdx.x, t = threadIdx.x;
    __shared__ int partial[256];
    __shared__ int res[2];
    int deg = (minb[b] == maxb[b]) ? 1 : 0;
    int nfg = (int)floorf(0.3f * (float)(int)roiSum[b]);
    int Bf = -1, rf = 0, Bb = -1, rb = 0;
    if (!deg && nfg > 0){
        const u32* hh = ghf + (size_t)b * NBV;
        int s = 0;
        for (int i = 0; i < 32; i++) s += (int)hh[NBV-1 - (t*32+i)];
        partial[t] = s;
        __syncthreads();
        if (t == 0){
            int cum = 0, q = 0;
            for (; q < 256; q++){ if (cum + partial[q] >= nfg) break; cum += partial[q]; }
            for (int i = 0; i < 32; i++){
                int bkt = NBV-1 - (q*32+i);
                int h = (int)hh[bkt];
                if (cum + h >= nfg){ res[0] = bkt; res[1] = nfg - cum; break; }
                cum += h;
            }
        }
        __syncthreads();
        Bf = res[0]; rf = res[1];
        __syncthreads();
    }
    if (!deg){
        const u32* hh = ghb + (size_t)b * NBV;
        int s = 0;
        for (int i = 0; i < 32; i++) s += (int)hh[t*32+i];
        partial[t] = s;
        __syncthreads();
        if (t == 0){
            int cum = 0, q = 0;
            for (; q < 256; q++){ if (cum + partial[q] >= NBGK) break; cum += partial[q]; }
            for (int i = 0; i < 32; i++){
                int bkt = q*32+i;
                int h = (int)hh[bkt];
                if (cum + h >= NBGK){ res[0] = bkt; res[1] = NBGK - cum; break; }
                cum += h;
            }
        }
        __syncthreads();
        Bb = res[0]; rb = res[1];
    }
    if (t == 0){
        int* p = prm + b * PN;
        p[0] = nfg; p[1] = deg; p[2] = Bf; p[3] = rf; p[4] = Bb; p[5] = rb;
    }
}

// K6: collect boundary-bucket candidates (value bits, pixel idx)
__global__ __launch_bounds__(256) void k_collect1(const float* __restrict__ x, const u32* __restrict__ roiE,
        const int* __restrict__ prm,
        uint2* __restrict__ candF, u32* __restrict__ cntF,
        uint2* __restrict__ candB, u32* __restrict__ cntB)
{
    __shared__ u32 words[256];
    int img = blockIdx.x >> 5;
    int blk = blockIdx.x & 31;
    int t = threadIdx.x;
    int Bf = prm[img*PN + 2];
    int Bb = prm[img*PN + 4];
    words[t] = roiE[(size_t)img*WPI + blk*256 + t];
    __syncthreads();
    const float4* c4 = (const float4*)x + (size_t)img * (HWP/4) + (size_t)blk * 2048;
    #pragma unroll
    for (int k = 0; k < 8; k++){
        float4 v4 = c4[k*256 + t];
        float vv[4] = {v4.x, v4.y, v4.z, v4.w};
        u32 nib = (words[k*32 + (t>>3)] >> ((t&7)*4)) & 0xFu;
        int pix0 = blk*8192 + k*1024 + t*4;
        #pragma unroll
        for (int c = 0; c < 4; c++){
            float vb = vv[c] + EPSF;
            int bkt = vbucket(vb);
            int pix = pix0 + c;
            if (bkt == Bb){
                u32 q = atomicAdd(&cntB[img], 1u);
                if (q < CAND_CAP) candB[(size_t)img*CAND_CAP + q] = make_uint2(__float_as_uint(vb), (u32)pix);
            }
            if (bkt == Bf && ((nib >> c) & 1u)){
                u32 q = atomicAdd(&cntF[img], 1u);
                if (q < CAND_CAP) candF[(size_t)img*CAND_CAP + q] = make_uint2(__float_as_uint(vb), (u32)pix);
            }
        }
    }
}

// K7: resolve exact (bits, idx) threshold within boundary bucket
__global__ __launch_bounds__(256) void k_resolve1(const uint2* __restrict__ candF, const u32* __restrict__ cntF,
        const uint2* __restrict__ candB, const u32* __restrict__ cntB, int* __restrict__ prm)
{
    int b = blockIdx.x, t = threadIdx.x;
    __shared__ uint2 c[CAND_CAP];
    int rf = prm[b*PN + 3];
    if (rf > 0){
        int m = (int)cntF[b]; m = m < CAND_CAP ? m : CAND_CAP;
        for (int i = t; i < m; i += 256) c[i] = candF[(size_t)b*CAND_CAP + i];
        __syncthreads();
        for (int i = t; i < m; i += 256){
            u32 ki = c[i].x, xi = c[i].y;
            int r = 0;
            for (int j = 0; j < m; j++){
                u32 kj = c[j].x, xj = c[j].y;
                r += (kj > ki) || (kj == ki && xj < xi);
            }
            if (r == rf - 1){ prm[b*PN + 6] = (int)ki; prm[b*PN + 7] = (int)xi; }
        }
    } else if (t == 0){
        prm[b*PN + 6] = (int)0xFFFFFFFFu; prm[b*PN + 7] = -1;
    }
    __syncthreads();
    int rb = prm[b*PN + 5];
    if (rb > 0){
        int m = (int)cntB[b]; m = m < CAND_CAP ? m : CAND_CAP;
        for (int i = t; i < m; i += 256) c[i] = candB[(size_t)b*CAND_CAP + i];
        __syncthreads();
        for (int i = t; i < m; i += 256){
            u32 ki = c[i].x, xi = c[i].y;
            int r = 0;
            for (int j = 0; j < m; j++){
                u32 kj = c[j].x, xj = c[j].y;
                r += (kj < ki) || (kj == ki && xj < xi);
            }
            if (r == rb - 1){ prm[b*PN + 8] = (int)ki; prm[b*PN + 9] = (int)xi; }
        }
    } else if (t == 0){
        prm[b*PN + 8] = 0; prm[b*PN + 9] = -1;
    }
}

// K8: score histograms for masked fg/bg pixels (interleaved, float4 u loads)
__global__ __launch_bounds__(256) void k_shist(const float* __restrict__ x, const u32* __restrict__ roiE,
        const float* __restrict__ ufg, const float* __restrict__ ubg, const int* __restrict__ prm,
        u32* __restrict__ shfG, u32* __restrict__ shbG)
{
    __shared__ u32 hf[NBS];
    __shared__ u32 hb[NBS];
    __shared__ u32 words[256];
    for (int i = threadIdx.x; i < NBS; i += 256){ hf[i] = 0u; hb[i] = 0u; }
    int img = blockIdx.x >> 5;
    int blk = blockIdx.x & 31;
    int t = threadIdx.x;
    words[t] = roiE[(size_t)img*WPI + blk*256 + t];
    __syncthreads();
    const int* p = prm + img*PN;
    u32 ubf = (u32)p[6]; int ibf = p[7];
    u32 ubb = (u32)p[8]; int ibb = p[9];
    size_t b4 = (size_t)img * (HWP/4) + (size_t)blk * 2048;
    const float4* c4 = (const float4*)x + b4;
    const float4* uf4 = (const float4*)ufg + b4;
    const float4* ub4 = (const float4*)ubg + b4;
    #pragma unroll
    for (int k = 0; k < 8; k++){
        float4 v4 = c4[k*256 + t];
        float vv[4] = {v4.x, v4.y, v4.z, v4.w};
        u32 nib = (words[k*32 + (t>>3)] >> ((t&7)*4)) & 0xFu;
        int pix0 = blk*8192 + k*1024 + t*4;
        float vbv[4]; bool fm[4], bm[4]; bool anyf = false, anyb = false;
        #pragma unroll
        for (int c = 0; c < 4; c++){
            float vb = vv[c] + EPSF;
            vbv[c] = vb;
            u32 bu = __float_as_uint(vb);
            int pix = pix0 + c;
            fm[c] = ((nib >> c) & 1u) && (bu > ubf || (bu == ubf && pix <= ibf));
            bm[c] = (bu < ubb || (bu == ubb && pix <= ibb));
            anyf |= fm[c]; anyb |= bm[c];
        }
        if (anyf){
            float4 u4 = uf4[k*256 + t];
            float uu[4] = {u4.x, u4.y, u4.z, u4.w};
            #pragma unroll
            for (int c = 0; c < 4; c++){
                if (fm[c]){
                    float s = logf(vbv[c]) - logf(-logf(uu[c]));
                    atomicAdd(&hf[sbucket(s)], 1u);
                }
            }
        }
        if (anyb){
            float4 u4 = ub4[k*256 + t];
            float uu[4] = {u4.x, u4.y, u4.z, u4.w};
            #pragma unroll
            for (int c = 0; c < 4; c++){
                if (bm[c]){
                    float pb = fmaxf(1.0f - vbv[c], 0.0f) + EPSF;
                    float s = logf(pb) - logf(-logf(uu[c]));
                    atomicAdd(&hb[sbucket(s)], 1u);
                }
            }
        }
    }
    __syncthreads();
    for (int i = t; i < NBS; i += 256){
        u32 h = hf[i]; if (h) atomicAdd(&shfG[(size_t)img*NBS + i], h);
        h = hb[i];     if (h) atomicAdd(&shbG[(size_t)img*NBS + i], h);
    }
}

// K8b: scan score hists -> boundary bucket + needed-from-boundary counts
__global__ __launch_bounds__(256) void k_bound2(const u32* __restrict__ shfG, const u32* __restrict__ shbG,
        int* __restrict__ prm)
{
    int b = blockIdx.x, t = threadIdx.x;
    __shared__ int partial[256];
    __shared__ int res[2];
    int* p = prm + b*PN;
    int nfg = p[0], deg = p[1];
    int kf = (deg || nfg <= 0) ? 0 : (nfg < 100 ? nfg : 100);
    int kb = deg ? 0 : 100;
    int sbf = 0x7FFFFFFF, needf = 0, sbb = 0x7FFFFFFF, needb = 0;
    if (kf > 0){
        const u32* hh = shfG + (size_t)b * NBS;
        int s = 0;
        for (int i = 0; i < 16; i++) s += (int)hh[NBS-1 - (t*16+i)];
        partial[t] = s;
        __syncthreads();
        if (t == 0){
            int cum = 0, q = 0;
            for (; q < 256; q++){ if (cum + partial[q] >= kf) break; cum += partial[q]; }
            for (int i = 0; i < 16; i++){
                int bkt = NBS-1 - (q*16+i);
                int h = (int)hh[bkt];
                if (cum + h >= kf){ res[0] = bkt; res[1] = kf - cum; break; }
                cum += h;
            }
        }
        __syncthreads();
        sbf = res[0]; needf = res[1];
        __syncthreads();
    }
    if (kb > 0){
        const u32* hh = shbG + (size_t)b * NBS;
        int s = 0;
        for (int i = 0; i < 16; i++) s += (int)hh[NBS-1 - (t*16+i)];
        partial[t] = s;
        __syncthreads();
        if (t == 0){
            int cum = 0, q = 0;
            for (; q < 256; q++){ if (cum + partial[q] >= kb) break; cum += partial[q]; }
            for (int i = 0; i < 16; i++){
                int bkt = NBS-1 - (q*16+i);
                int h = (int)hh[bkt];
                if (cum + h >= kb){ res[0] = bkt; res[1] = kb - cum; break; }
                cum += h;
            }
        }
        __syncthreads();
        sbb = res[0]; needb = res[1];
    }
    if (t == 0){
        p[10] = sbf; p[12] = needf; p[13] = sbb; p[15] = needb; p[16] = kf; p[17] = kb;
    }
}

// K9: collect score winners (above boundary bucket) + boundary candidates
__global__ __launch_bounds__(256) void k_collect2(const float* __restrict__ x, const u32* __restrict__ roiE,
        const float* __restrict__ ufg, const float* __restrict__ ubg, const int* __restrict__ prm,
        uint2* __restrict__ selF, u32* __restrict__ cntSelF, uint2* __restrict__ scandF, u32* __restrict__ cntScF,
        uint2* __restrict__ selB, u32* __restrict__ cntSelB, uint2* __restrict__ scandB, u32* __restrict__ cntScB)
{
    __shared__ u32 words[256];
    int img = blockIdx.x >> 5;
    int blk = blockIdx.x & 31;
    int t = threadIdx.x;
    words[t] = roiE[(size_t)img*WPI + blk*256 + t];
    __syncthreads();
    const int* p = prm + img*PN;
    u32 ubf = (u32)p[6]; int ibf = p[7];
    u32 ubb = (u32)p[8]; int ibb = p[9];
    int sbf = p[10], sbb = p[13];
    size_t b4 = (size_t)img * (HWP/4) + (size_t)blk * 2048;
    const float4* c4 = (const float4*)x + b4;
    const float4* uf4 = (const float4*)ufg + b4;
    const float4* ub4 = (const float4*)ubg + b4;
    #pragma unroll
    for (int k = 0; k < 8; k++){
        float4 v4 = c4[k*256 + t];
        float vv[4] = {v4.x, v4.y, v4.z, v4.w};
        u32 nib = (words[k*32 + (t>>3)] >> ((t&7)*4)) & 0xFu;
        int pix0 = blk*8192 + k*1024 + t*4;
        float vbv[4]; bool fm[4], bm[4]; bool anyf = false, anyb = false;
        #pragma unroll
        for (int c = 0; c < 4; c++){
            float vb = vv[c] + EPSF;
            vbv[c] = vb;
            u32 bu = __float_as_uint(vb);
            int pix = pix0 + c;
            fm[c] = ((nib >> c) & 1u) && (bu > ubf || (bu == ubf && pix <= ibf));
            bm[c] = (bu < ubb || (bu == ubb && pix <= ibb));
            anyf |= fm[c]; anyb |= bm[c];
        }
        if (anyf){
            float4 u4 = uf4[k*256 + t];
            float uu[4] = {u4.x, u4.y, u4.z, u4.w};
            #pragma unroll
            for (int c = 0; c < 4; c++){
                if (fm[c]){
                    float s = logf(vbv[c]) - logf(-logf(uu[c]));
                    int sb = sbucket(s);
                    if (sb > sbf){
                        u32 q = atomicAdd(&cntSelF[img], 1u);
                        if (q < SEL_CAP) selF[(size_t)img*SEL_CAP + q] = make_uint2(flipf(s), (u32)(pix0 + c));
                    } else if (sb == sbf){
                        u32 q = atomicAdd(&cntScF[img], 1u);
                        if (q < CAND_CAP) scandF[(size_t)img*CAND_CAP + q] = make_uint2(flipf(s), (u32)(pix0 + c));
                    }
                }
            }
        }
        if (anyb){
            float4 u4 = ub4[k*256 + t];
            float uu[4] = {u4.x, u4.y, u4.z, u4.w};
            #pragma unroll
            for (int c = 0; c < 4; c++){
                if (bm[c]){
                    float pb = fmaxf(1.0f - vbv[c], 0.0f) + EPSF;
                    float s = logf(pb) - logf(-logf(uu[c]));
                    int sb = sbucket(s);
                    if (sb > sbb){
                        u32 q = atomicAdd(&cntSelB[img], 1u);
                        if (q < SEL_CAP) selB[(size_t)img*SEL_CAP + q] = make_uint2(flipf(s), (u32)(pix0 + c));
                    } else if (sb == sbb){
                        u32 q = atomicAdd(&cntScB[img], 1u);
                        if (q < CAND_CAP) scandB[(size_t)img*CAND_CAP + q] = make_uint2(flipf(s), (u32)(pix0 + c));
                    }
                }
            }
        }
    }
}

// K11: finalize top-k seed sets + 3x3 dilation paint with overlap cancel
__global__ __launch_bounds__(256) void k_final(
        const uint2* __restrict__ selF, const u32* __restrict__ cntSelF,
        const uint2* __restrict__ scandF, const u32* __restrict__ cntScF,
        const uint2* __restrict__ selB, const u32* __restrict__ cntSelB,
        const uint2* __restrict__ scandB, const u32* __restrict__ cntScB,
        const int* __restrict__ prm, int* __restrict__ out)
{
    int b = blockIdx.x, t = threadIdx.x;
    __shared__ uint2 c[CAND_CAP];
    __shared__ int seedF[SEL_CAP];
    __shared__ int seedB[SEL_CAP];
    __shared__ int nF, nB;
    const int* p = prm + b*PN;
    int needf = p[12], needb = p[15];

    // FG
    int c0 = (int)cntSelF[b]; c0 = c0 < SEL_CAP ? c0 : SEL_CAP;
    for (int i = t; i < c0; i += 256) seedF[i] = (int)selF[(size_t)b*SEL_CAP + i].y;
    int m = (int)cntScF[b]; m = m < CAND_CAP ? m : CAND_CAP;
    for (int i = t; i < m; i += 256) c[i] = scandF[(size_t)b*CAND_CAP + i];
    if (t == 0){ nF = c0; nB = 0; }
    __syncthreads();
    for (int i = t; i < m; i += 256){
        u32 ki = c[i].x, xi = c[i].y;
        int r = 0;
        for (int j = 0; j < m; j++){
            u32 kj = c[j].x, xj = c[j].y;
            r += (kj > ki) || (kj == ki && xj < xi);
        }
        if (r < needf){
            int q = atomicAdd(&nF, 1);
            if (q < SEL_CAP) seedF[q] = (int)xi;
        }
    }
    __syncthreads();
    int fN = nF; fN = fN < SEL_CAP ? fN : SEL_CAP;
    __syncthreads();

    // BG
    int c0b = (int)cntSelB[b]; c0b = c0b < SEL_CAP ? c0b : SEL_CAP;
    for (int i = t; i < c0b; i += 256) seedB[i] = (int)selB[(size_t)b*SEL_CAP + i].y;
    int mb = (int)cntScB[b]; mb = mb < CAND_CAP ? mb : CAND_CAP;
    for (int i = t; i < mb; i += 256) c[i] = scandB[(size_t)b*CAND_CAP + i];
    if (t == 0) nB = c0b;
    __syncthreads();
    for (int i = t; i < mb; i += 256){
        u32 ki = c[i].x, xi = c[i].y;
        int r = 0;
        for (int j = 0; j < mb; j++){
            u32 kj = c[j].x, xj = c[j].y;
            r += (kj > ki) || (kj == ki && xj < xi);
        }
        if (r < needb){
            int q = atomicAdd(&nB, 1);
            if (q < SEL_CAP) seedB[q] = (int)xi;
        }
    }
    __syncthreads();
    int bN = nB; bN = bN < SEL_CAP ? bN : SEL_CAP;
    __syncthreads();

    int* outp = out + (size_t)b * HWP;
    for (int task = t; task < fN * 9; task += 256){
        int s = seedF[task / 9];
        int o = task % 9;
        int y = (s >> 9) + (o / 3) - 1;
        int xx = (s & 511) + (o % 3) - 1;
        if (y < 0 || y >= HH || xx < 0 || xx >= WW) continue;
        bool conf = false;
        for (int j = 0; j < bN; j++){
            int sb2 = seedB[j];
            int dy = y - (sb2 >> 9); if (dy < 0) dy = -dy;
            int dx = xx - (sb2 & 511); if (dx < 0) dx = -dx;
            if (dy <= 1 && dx <= 1){ conf = true; break; }
        }
        if (!conf) outp[y * WW + xx] = 1;
    }
    for (int task = t; task < bN * 9; task += 256){
        int s = seedB[task / 9];
        int o = task % 9;
        int y = (s >> 9) + (o / 3) - 1;
        int xx = (s & 511) + (o % 3) - 1;
        if (y < 0 || y >= HH || xx < 0 || xx >= WW) continue;
        bool conf = false;
        for (int j = 0; j < fN; j++){
            int sf2 = seedF[j];
            int dy = y - (sf2 >> 9); if (dy < 0) dy = -dy;
            int dx = xx - (sf2 & 511); if (dx < 0) dx = -dx;
            if (dy <= 1 && dx <= 1){ conf = true; break; }
        }
        if (!conf) outp[y * WW + xx] = 0;
    }
}

extern "C" void kernel_launch(void* const* d_in, const int* in_sizes, int n_in,
                              void* d_out, int out_size, void* d_ws, size_t ws_size,
                              hipStream_t stream)
{
    (void)in_sizes; (void)n_in; (void)out_size; (void)ws_size;
    const float* x   = (const float*)d_in[0];
    const float* thr = (const float*)d_in[1];
    const float* ufg = (const float*)d_in[2];
    const float* ubg = (const float*)d_in[3];
    int* out = (int*)d_out;
    char* ws = (char*)d_ws;

    size_t off = 0;
    auto carve = [&](size_t bytes) -> char* {
        char* ptr = ws + off;
        off = (off + bytes + 255) & ~(size_t)255;
        return ptr;
    };
    u32* ghist_bg = (u32*)carve((size_t)BB*NBV*4);
    u32* ghist_fg = (u32*)carve((size_t)BB*NBV*4);
    u32* shf      = (u32*)carve((size_t)BB*NBS*4);
    u32* shb      = (u32*)carve((size_t)BB*NBS*4);
    u32* cnts     = (u32*)carve((size_t)6*BB*4);
    u32* maxb     = (u32*)carve((size_t)BB*4);
    u32* roiSum   = (u32*)carve((size_t)BB*4);
    size_t zero_bytes = off;
    u32* minb     = (u32*)carve((size_t)BB*4);
    size_t minb_off = (size_t)((char*)minb - ws);
    u32* roi0     = (u32*)carve((size_t)BB*WPI*4);
    u32* roiE     = (u32*)carve((size_t)BB*WPI*4);
    int* prm      = (int*)carve((size_t)BB*PN*4);
    uint2* candF  = (uint2*)carve((size_t)BB*CAND_CAP*8);
    uint2* candB  = (uint2*)carve((size_t)BB*CAND_CAP*8);
    uint2* scandF = (uint2*)carve((size_t)BB*CAND_CAP*8);
    uint2* scandB = (uint2*)carve((size_t)BB*CAND_CAP*8);
    uint2* selF   = (uint2*)carve((size_t)BB*SEL_CAP*8);
    uint2* selB   = (uint2*)carve((size_t)BB*SEL_CAP*8);
    u32* cntF = cnts, *cntB = cnts + BB, *cntSelF = cnts + 2*BB,
       *cntScF = cnts + 3*BB, *cntSelB = cnts + 4*BB, *cntScB = cnts + 5*BB;

    hipMemsetAsync(ws, 0, zero_bytes, stream);
    hipMemsetAsync(ws + minb_off, 0xFF, (size_t)BB*4, stream);

    k_prep    <<<2048, 256, 0, stream>>>(x, thr, roi0, ghist_bg, minb, maxb, out);
    k_erode   <<<64,   256, 0, stream>>>(roi0, roiE, roiSum);
    k_fghist  <<<2048, 256, 0, stream>>>(x, roiE, ghist_fg);
    k_bound1  <<<64,   256, 0, stream>>>(ghist_fg, ghist_bg, minb, maxb, roiSum, prm);
    k_collect1<<<2048, 256, 0, stream>>>(x, roiE, prm, candF, cntF, candB, cntB);
    k_resolve1<<<64,   256, 0, stream>>>(candF, cntF, candB, cntB, prm);
    k_shist   <<<2048, 256, 0, stream>>>(x, roiE, ufg, ubg, prm, shf, shb);
    k_bound2  <<<64,   256, 0, stream>>>(shf, shb, prm);
    k_collect2<<<2048, 256, 0, stream>>>(x, roiE, ufg, ubg, prm,
                                         selF, cntSelF, scandF, cntScF,
                                         selB, cntSelB, scandB, cntScB);
    k_final   <<<64,   256, 0, stream>>>(selF, cntSelF, scandF, cntScF,
                                         selB, cntSelB, scandB, cntScB, prm, out);
}

// Round 3
// 470.272 us; speedup vs baseline: 1.6392x; 1.0546x over previous
//
#include <hip/hip_runtime.h>

typedef unsigned int u32;

#define BB 64
#define HH 512
#define WW 512
#define HWP 262144            // 512*512
#define WPI 8192              // words per image (512*16)
#define NBV 8192              // value histogram bins
#define NBS 4096              // score histogram bins
#define EPSF 1e-8f
#define NBGK 78643            // int(0.3 * 512*512)
#define CAND_CAP 4096
#define SEL_CAP 128
#define PN 20
#define TA 1024

// prm fields per image:
// 0 nfg, 1 deg, 2 Bf, 3 rf, 4 Bb, 5 rb, 6 ubf, 7 ibf, 8 ubb, 9 ibb,
// 10 sbf, 12 needf, 13 sbb, 15 needb, 16 kf, 17 kb

__device__ __forceinline__ int vbucket(float vb){
    int b = (int)(vb * 8192.0f);
    b = b < 0 ? 0 : b;
    return b > (NBV-1) ? (NBV-1) : b;
}
__device__ __forceinline__ int sbucket(float s){
    float a = (s + 24.0f) * (4096.0f / 44.0f);
    a = fmaxf(a, 0.0f);
    int b = (int)a;
    return b > (NBS-1) ? (NBS-1) : b;
}
__device__ __forceinline__ u32 flipf(float s){
    u32 u = __float_as_uint(s);
    u32 m = (u & 0x80000000u) ? 0xFFFFFFFFu : 0x80000000u;
    return u ^ m;
}

// K_A: block-per-image. ROI bits -> erode -> roiE/roiSum, value hists (LDS),
// bound scan, boundary-candidate collect + exact rank resolve -> prm[0..9].
__global__ __launch_bounds__(TA) void k_roi(const float* __restrict__ x,
        const float* __restrict__ thr, u32* __restrict__ roiE, int* __restrict__ prm)
{
    __shared__ __align__(16) u32 S[3*WPI];   // 96KB: A | HB | HF
    __shared__ int partial[TA];
    __shared__ int res2[2];
    __shared__ u32 sMin, sMax, sCnt;
    __shared__ int cF, cB;
    u32* A  = S;            // roi bits (raw, then eroded)
    u32* HB = S + WPI;      // bg value hist, then candF overlay
    u32* HF = S + 2*WPI;    // H-erode temp, then fg hist, then candB overlay
    int img = blockIdx.x, t = threadIdx.x;

    for (int i = t; i < WPI; i += TA){ A[i] = 0u; HB[i] = 0u; }
    if (t == 0){ sMin = 0xFFFFFFFFu; sMax = 0u; sCnt = 0u; }
    __syncthreads();

    const float4* c4 = (const float4*)x + (size_t)img * (HWP/4);
    float th = thr[img];
    th = (th == 0.0f) ? 1.0f : ((th == 255.0f) ? 254.0f : th);
    u32 mn = 0xFFFFFFFFu, mx = 0u;
    for (int k = 0; k < 64; k++){
        int fi = k*TA + t;
        float4 v4 = c4[fi];
        float vv[4] = {v4.x, v4.y, v4.z, v4.w};
        u32 nib = 0u;
        #pragma unroll
        for (int c = 0; c < 4; c++){
            float v = vv[c];
            u32 ub = __float_as_uint(v);
            mn = mn < ub ? mn : ub;
            mx = mx > ub ? mx : ub;
            if (floorf(v * 255.0f) > th) nib |= (1u << c);
            atomicAdd(&HB[vbucket(v + EPSF)], 1u);
        }
        if (nib) atomicOr(&A[fi >> 3], nib << ((fi & 7) * 4));
    }
    for (int o = 32; o >= 1; o >>= 1){
        u32 m2 = __shfl_down(mn, o); mn = mn < m2 ? mn : m2;
        u32 m3 = __shfl_down(mx, o); mx = mx > m3 ? mx : m3;
    }
    if ((t & 63) == 0){ atomicMin(&sMin, mn); atomicMax(&sMax, mx); }
    __syncthreads();

    // H-erode A -> HF
    for (int i = t; i < WPI; i += TA){
        int wr = i & 15;
        u32 cur = A[i];
        u32 left  = (wr > 0)  ? A[i-1] : 0xFFFFFFFFu;
        u32 right = (wr < 15) ? A[i+1] : 0xFFFFFFFFu;
        u32 res = cur;
        #pragma unroll
        for (int d = 1; d <= 5; d++){
            res &= (cur >> d) | (right << (32 - d));
            res &= (cur << d) | (left  >> (32 - d));
        }
        HF[i] = res;
    }
    __syncthreads();
    // V-erode HF -> A, write roiE, popcount
    u32 cnt = 0u;
    u32* dst = roiE + (size_t)img * WPI;
    for (int i = t; i < WPI; i += TA){
        int r = i >> 4;
        u32 res = 0xFFFFFFFFu;
        #pragma unroll
        for (int d = -5; d <= 5; d++){
            int rr = r + d;
            if (rr >= 0 && rr < HH) res &= HF[i + d*16];
        }
        A[i] = res;
        dst[i] = res;
        cnt += __popc(res);
    }
    for (int o = 32; o >= 1; o >>= 1) cnt += __shfl_down(cnt, o);
    if ((t & 63) == 0) atomicAdd(&sCnt, cnt);
    __syncthreads();

    int roiSum = (int)sCnt;
    int deg = (sMin == sMax) ? 1 : 0;
    int nfg = (int)floorf(0.3f * (float)roiSum);

    // fg hist into HF
    for (int i = t; i < WPI; i += TA) HF[i] = 0u;
    __syncthreads();
    for (int k = 0; k < 64; k++){
        int fi = k*TA + t;
        u32 nib = (A[fi >> 3] >> ((fi & 7) * 4)) & 0xFu;
        if (nib){
            float4 v4 = c4[fi];
            float vv[4] = {v4.x, v4.y, v4.z, v4.w};
            #pragma unroll
            for (int c = 0; c < 4; c++){
                if ((nib >> c) & 1u) atomicAdd(&HF[vbucket(vv[c] + EPSF)], 1u);
            }
        }
    }
    __syncthreads();

    // bound scans
    int Bf = -1, rf = 0, Bb = -1, rb = 0;
    if (!deg && nfg > 0){
        int s = 0;
        for (int i = 0; i < 8; i++) s += (int)HF[NBV-1 - (t*8+i)];
        partial[t] = s;
        __syncthreads();
        if (t == 0){
            int cum = 0, q = 0;
            for (; q < TA; q++){ if (cum + partial[q] >= nfg) break; cum += partial[q]; }
            for (int i = 0; i < 8; i++){
                int bkt = NBV-1 - (q*8+i);
                int h = (int)HF[bkt];
                if (cum + h >= nfg){ res2[0] = bkt; res2[1] = nfg - cum; break; }
                cum += h;
            }
        }
        __syncthreads();
        Bf = res2[0]; rf = res2[1];
        __syncthreads();
    }
    if (!deg){
        int s = 0;
        for (int i = 0; i < 8; i++) s += (int)HB[t*8+i];
        partial[t] = s;
        __syncthreads();
        if (t == 0){
            int cum = 0, q = 0;
            for (; q < TA; q++){ if (cum + partial[q] >= NBGK) break; cum += partial[q]; }
            for (int i = 0; i < 8; i++){
                int bkt = q*8+i;
                int h = (int)HB[bkt];
                if (cum + h >= NBGK){ res2[0] = bkt; res2[1] = NBGK - cum; break; }
                cum += h;
            }
        }
        __syncthreads();
        Bb = res2[0]; rb = res2[1];
        __syncthreads();
    }

    // collect boundary candidates (candF overlays HB, candB overlays HF)
    uint2* candF = (uint2*)HB;
    uint2* candB = (uint2*)HF;
    if (t == 0){ cF = 0; cB = 0; }
    __syncthreads();
    for (int k = 0; k < 64; k++){
        int fi = k*TA + t;
        float4 v4 = c4[fi];
        float vv[4] = {v4.x, v4.y, v4.z, v4.w};
        u32 nib = (A[fi >> 3] >> ((fi & 7) * 4)) & 0xFu;
        #pragma unroll
        for (int c = 0; c < 4; c++){
            float vb = vv[c] + EPSF;
            int bkt = vbucket(vb);
            int pix = fi*4 + c;
            if (bkt == Bb){
                int q = atomicAdd(&cB, 1);
                if (q < CAND_CAP) candB[q] = make_uint2(__float_as_uint(vb), (u32)pix);
            }
            if (bkt == Bf && ((nib >> c) & 1u)){
                int q = atomicAdd(&cF, 1);
                if (q < CAND_CAP) candF[q] = make_uint2(__float_as_uint(vb), (u32)pix);
            }
        }
    }
    __syncthreads();

    // rank resolve
    int* p = prm + img * PN;
    if (rf > 0){
        int m = cF; m = m < CAND_CAP ? m : CAND_CAP;
        for (int i = t; i < m; i += TA){
            u32 ki = candF[i].x, xi = candF[i].y;
            int r = 0;
            for (int j = 0; j < m; j++){
                u32 kj = candF[j].x, xj = candF[j].y;
                r += (kj > ki) || (kj == ki && xj < xi);
            }
            if (r == rf - 1){ p[6] = (int)ki; p[7] = (int)xi; }
        }
    } else if (t == 0){
        p[6] = (int)0xFFFFFFFFu; p[7] = -1;
    }
    if (rb > 0){
        int m = cB; m = m < CAND_CAP ? m : CAND_CAP;
        for (int i = t; i < m; i += TA){
            u32 ki = candB[i].x, xi = candB[i].y;
            int r = 0;
            for (int j = 0; j < m; j++){
                u32 kj = candB[j].x, xj = candB[j].y;
                r += (kj < ki) || (kj == ki && xj < xi);
            }
            if (r == rb - 1){ p[8] = (int)ki; p[9] = (int)xi; }
        }
    } else if (t == 0){
        p[8] = 0; p[9] = -1;
    }
    if (t == 0){
        p[0] = nfg; p[1] = deg; p[2] = Bf; p[3] = rf; p[4] = Bb; p[5] = rb;
    }
}

// XCD-local remap for 2048-block streamers: all 32 blocks of an image keep the
// same (bid & 7) residue -> same XCD under round-robin dispatch (heuristic).
__device__ __forceinline__ void imgblk(int bid, int& img, int& blk){
    int r = bid & 7, s = bid >> 3;
    img = ((s >> 5) << 3) | r;
    blk = s & 31;
}

// K8: score histograms for masked fg/bg pixels
__global__ __launch_bounds__(256) void k_shist(const float* __restrict__ x, const u32* __restrict__ roiE,
        const float* __restrict__ ufg, const float* __restrict__ ubg, const int* __restrict__ prm,
        u32* __restrict__ shfG, u32* __restrict__ shbG)
{
    __shared__ u32 hf[NBS];
    __shared__ u32 hb[NBS];
    __shared__ u32 words[256];
    for (int i = threadIdx.x; i < NBS; i += 256){ hf[i] = 0u; hb[i] = 0u; }
    int img, blk;
    imgblk(blockIdx.x, img, blk);
    int t = threadIdx.x;
    words[t] = roiE[(size_t)img*WPI + blk*256 + t];
    __syncthreads();
    const int* p = prm + img*PN;
    u32 ubf = (u32)p[6]; int ibf = p[7];
    u32 ubb = (u32)p[8]; int ibb = p[9];
    size_t b4 = (size_t)img * (HWP/4) + (size_t)blk * 2048;
    const float4* c4 = (const float4*)x + b4;
    const float4* uf4 = (const float4*)ufg + b4;
    const float4* ub4 = (const float4*)ubg + b4;
    #pragma unroll
    for (int k = 0; k < 8; k++){
        float4 v4 = c4[k*256 + t];
        float vv[4] = {v4.x, v4.y, v4.z, v4.w};
        u32 nib = (words[k*32 + (t>>3)] >> ((t&7)*4)) & 0xFu;
        int pix0 = blk*8192 + k*1024 + t*4;
        float vbv[4]; bool fm[4], bm[4]; bool anyf = false, anyb = false;
        #pragma unroll
        for (int c = 0; c < 4; c++){
            float vb = vv[c] + EPSF;
            vbv[c] = vb;
            u32 bu = __float_as_uint(vb);
            int pix = pix0 + c;
            fm[c] = ((nib >> c) & 1u) && (bu > ubf || (bu == ubf && pix <= ibf));
            bm[c] = (bu < ubb || (bu == ubb && pix <= ibb));
            anyf |= fm[c]; anyb |= bm[c];
        }
        if (anyf){
            float4 u4 = uf4[k*256 + t];
            float uu[4] = {u4.x, u4.y, u4.z, u4.w};
            #pragma unroll
            for (int c = 0; c < 4; c++){
                if (fm[c]){
                    float s = logf(vbv[c]) - logf(-logf(uu[c]));
                    atomicAdd(&hf[sbucket(s)], 1u);
                }
            }
        }
        if (anyb){
            float4 u4 = ub4[k*256 + t];
            float uu[4] = {u4.x, u4.y, u4.z, u4.w};
            #pragma unroll
            for (int c = 0; c < 4; c++){
                if (bm[c]){
                    float pb = fmaxf(1.0f - vbv[c], 0.0f) + EPSF;
                    float s = logf(pb) - logf(-logf(uu[c]));
                    atomicAdd(&hb[sbucket(s)], 1u);
                }
            }
        }
    }
    __syncthreads();
    for (int i = t; i < NBS; i += 256){
        u32 h = hf[i]; if (h) atomicAdd(&shfG[(size_t)img*NBS + i], h);
        h = hb[i];     if (h) atomicAdd(&shbG[(size_t)img*NBS + i], h);
    }
}

// K8b: scan score hists -> boundary bucket + needed-from-boundary counts
__global__ __launch_bounds__(256) void k_bound2(const u32* __restrict__ shfG, const u32* __restrict__ shbG,
        int* __restrict__ prm)
{
    int b = blockIdx.x, t = threadIdx.x;
    __shared__ int partial[256];
    __shared__ int res[2];
    int* p = prm + b*PN;
    int nfg = p[0], deg = p[1];
    int kf = (deg || nfg <= 0) ? 0 : (nfg < 100 ? nfg : 100);
    int kb = deg ? 0 : 100;
    int sbf = 0x7FFFFFFF, needf = 0, sbb = 0x7FFFFFFF, needb = 0;
    if (kf > 0){
        const u32* hh = shfG + (size_t)b * NBS;
        int s = 0;
        for (int i = 0; i < 16; i++) s += (int)hh[NBS-1 - (t*16+i)];
        partial[t] = s;
        __syncthreads();
        if (t == 0){
            int cum = 0, q = 0;
            for (; q < 256; q++){ if (cum + partial[q] >= kf) break; cum += partial[q]; }
            for (int i = 0; i < 16; i++){
                int bkt = NBS-1 - (q*16+i);
                int h = (int)hh[bkt];
                if (cum + h >= kf){ res[0] = bkt; res[1] = kf - cum; break; }
                cum += h;
            }
        }
        __syncthreads();
        sbf = res[0]; needf = res[1];
        __syncthreads();
    }
    if (kb > 0){
        const u32* hh = shbG + (size_t)b * NBS;
        int s = 0;
        for (int i = 0; i < 16; i++) s += (int)hh[NBS-1 - (t*16+i)];
        partial[t] = s;
        __syncthreads();
        if (t == 0){
            int cum = 0, q = 0;
            for (; q < 256; q++){ if (cum + partial[q] >= kb) break; cum += partial[q]; }
            for (int i = 0; i < 16; i++){
                int bkt = NBS-1 - (q*16+i);
                int h = (int)hh[bkt];
                if (cum + h >= kb){ res[0] = bkt; res[1] = kb - cum; break; }
                cum += h;
            }
        }
        __syncthreads();
        sbb = res[0]; needb = res[1];
    }
    if (t == 0){
        p[10] = sbf; p[12] = needf; p[13] = sbb; p[15] = needb; p[16] = kf; p[17] = kb;
    }
}

// K9: collect score winners (above boundary bucket) + boundary candidates
__global__ __launch_bounds__(256) void k_collect2(const float* __restrict__ x, const u32* __restrict__ roiE,
        const float* __restrict__ ufg, const float* __restrict__ ubg, const int* __restrict__ prm,
        uint2* __restrict__ selF, u32* __restrict__ cntSelF, uint2* __restrict__ scandF, u32* __restrict__ cntScF,
        uint2* __restrict__ selB, u32* __restrict__ cntSelB, uint2* __restrict__ scandB, u32* __restrict__ cntScB)
{
    __shared__ u32 words[256];
    int img, blk;
    imgblk(blockIdx.x, img, blk);
    int t = threadIdx.x;
    words[t] = roiE[(size_t)img*WPI + blk*256 + t];
    __syncthreads();
    const int* p = prm + img*PN;
    u32 ubf = (u32)p[6]; int ibf = p[7];
    u32 ubb = (u32)p[8]; int ibb = p[9];
    int sbf = p[10], sbb = p[13];
    size_t b4 = (size_t)img * (HWP/4) + (size_t)blk * 2048;
    const float4* c4 = (const float4*)x + b4;
    const float4* uf4 = (const float4*)ufg + b4;
    const float4* ub4 = (const float4*)ubg + b4;
    #pragma unroll
    for (int k = 0; k < 8; k++){
        float4 v4 = c4[k*256 + t];
        float vv[4] = {v4.x, v4.y, v4.z, v4.w};
        u32 nib = (words[k*32 + (t>>3)] >> ((t&7)*4)) & 0xFu;
        int pix0 = blk*8192 + k*1024 + t*4;
        float vbv[4]; bool fm[4], bm[4]; bool anyf = false, anyb = false;
        #pragma unroll
        for (int c = 0; c < 4; c++){
            float vb = vv[c] + EPSF;
            vbv[c] = vb;
            u32 bu = __float_as_uint(vb);
            int pix = pix0 + c;
            fm[c] = ((nib >> c) & 1u) && (bu > ubf || (bu == ubf && pix <= ibf));
            bm[c] = (bu < ubb || (bu == ubb && pix <= ibb));
            anyf |= fm[c]; anyb |= bm[c];
        }
        if (anyf){
            float4 u4 = uf4[k*256 + t];
            float uu[4] = {u4.x, u4.y, u4.z, u4.w};
            #pragma unroll
            for (int c = 0; c < 4; c++){
                if (fm[c]){
                    float s = logf(vbv[c]) - logf(-logf(uu[c]));
                    int sb = sbucket(s);
                    if (sb > sbf){
                        u32 q = atomicAdd(&cntSelF[img], 1u);
                        if (q < SEL_CAP) selF[(size_t)img*SEL_CAP + q] = make_uint2(flipf(s), (u32)(pix0 + c));
                    } else if (sb == sbf){
                        u32 q = atomicAdd(&cntScF[img], 1u);
                        if (q < CAND_CAP) scandF[(size_t)img*CAND_CAP + q] = make_uint2(flipf(s), (u32)(pix0 + c));
                    }
                }
            }
        }
        if (anyb){
            float4 u4 = ub4[k*256 + t];
            float uu[4] = {u4.x, u4.y, u4.z, u4.w};
            #pragma unroll
            for (int c = 0; c < 4; c++){
                if (bm[c]){
                    float pb = fmaxf(1.0f - vbv[c], 0.0f) + EPSF;
                    float s = logf(pb) - logf(-logf(uu[c]));
                    int sb = sbucket(s);
                    if (sb > sbb){
                        u32 q = atomicAdd(&cntSelB[img], 1u);
                        if (q < SEL_CAP) selB[(size_t)img*SEL_CAP + q] = make_uint2(flipf(s), (u32)(pix0 + c));
                    } else if (sb == sbb){
                        u32 q = atomicAdd(&cntScB[img], 1u);
                        if (q < CAND_CAP) scandB[(size_t)img*CAND_CAP + q] = make_uint2(flipf(s), (u32)(pix0 + c));
                    }
                }
            }
        }
    }
}

// K10: finalize top-k seed sets -> global seed lists
__global__ __launch_bounds__(256) void k_seeds(
        const uint2* __restrict__ selF, const u32* __restrict__ cntSelF,
        const uint2* __restrict__ scandF, const u32* __restrict__ cntScF,
        const uint2* __restrict__ selB, const u32* __restrict__ cntSelB,
        const uint2* __restrict__ scandB, const u32* __restrict__ cntScB,
        const int* __restrict__ prm,
        int* __restrict__ gSeedF, int* __restrict__ gnF,
        int* __restrict__ gSeedB, int* __restrict__ gnB)
{
    int b = blockIdx.x, t = threadIdx.x;
    __shared__ uint2 c[CAND_CAP];
    __shared__ int seedF[SEL_CAP];
    __shared__ int seedB[SEL_CAP];
    __shared__ int nF, nB;
    const int* p = prm + b*PN;
    int needf = p[12], needb = p[15];

    int c0 = (int)cntSelF[b]; c0 = c0 < SEL_CAP ? c0 : SEL_CAP;
    for (int i = t; i < c0; i += 256) seedF[i] = (int)selF[(size_t)b*SEL_CAP + i].y;
    int m = (int)cntScF[b]; m = m < CAND_CAP ? m : CAND_CAP;
    for (int i = t; i < m; i += 256) c[i] = scandF[(size_t)b*CAND_CAP + i];
    if (t == 0){ nF = c0; nB = 0; }
    __syncthreads();
    for (int i = t; i < m; i += 256){
        u32 ki = c[i].x, xi = c[i].y;
        int r = 0;
        for (int j = 0; j < m; j++){
            u32 kj = c[j].x, xj = c[j].y;
            r += (kj > ki) || (kj == ki && xj < xi);
        }
        if (r < needf){
            int q = atomicAdd(&nF, 1);
            if (q < SEL_CAP) seedF[q] = (int)xi;
        }
    }
    __syncthreads();
    int fN = nF; fN = fN < SEL_CAP ? fN : SEL_CAP;
    __syncthreads();

    int c0b = (int)cntSelB[b]; c0b = c0b < SEL_CAP ? c0b : SEL_CAP;
    for (int i = t; i < c0b; i += 256) seedB[i] = (int)selB[(size_t)b*SEL_CAP + i].y;
    int mb = (int)cntScB[b]; mb = mb < CAND_CAP ? mb : CAND_CAP;
    for (int i = t; i < mb; i += 256) c[i] = scandB[(size_t)b*CAND_CAP + i];
    if (t == 0) nB = c0b;
    __syncthreads();
    for (int i = t; i < mb; i += 256){
        u32 ki = c[i].x, xi = c[i].y;
        int r = 0;
        for (int j = 0; j < mb; j++){
            u32 kj = c[j].x, xj = c[j].y;
            r += (kj > ki) || (kj == ki && xj < xi);
        }
        if (r < needb){
            int q = atomicAdd(&nB, 1);
            if (q < SEL_CAP) seedB[q] = (int)xi;
        }
    }
    __syncthreads();
    int bN = nB; bN = bN < SEL_CAP ? bN : SEL_CAP;

    for (int i = t; i < fN; i += 256) gSeedF[b*SEL_CAP + i] = seedF[i];
    for (int i = t; i < bN; i += 256) gSeedB[b*SEL_CAP + i] = seedB[i];
    if (t == 0){ gnF[b] = fN; gnB[b] = bN; }
}

// K11: fill -255 and paint 3x3-dilated seeds with cross-set cancel
__global__ __launch_bounds__(256) void k_paint(
        const int* __restrict__ gSeedF, const int* __restrict__ gnF,
        const int* __restrict__ gSeedB, const int* __restrict__ gnB,
        int* __restrict__ out)
{
    __shared__ int sF[SEL_CAP], sB[SEL_CAP];
    int img = blockIdx.x >> 5, blk = blockIdx.x & 31, t = threadIdx.x;
    int fN = gnF[img]; fN = fN < SEL_CAP ? fN : SEL_CAP;
    int bN = gnB[img]; bN = bN < SEL_CAP ? bN : SEL_CAP;
    for (int i = t; i < fN; i += 256) sF[i] = gSeedF[img*SEL_CAP + i];
    for (int i = t; i < bN; i += 256) sB[i] = gSeedB[img*SEL_CAP + i];
    int4* o4 = (int4*)(out + (size_t)img*HWP + blk*8192);
    for (int i = t; i < 2048; i += 256) o4[i] = make_int4(-255,-255,-255,-255);
    __syncthreads();
    int row0 = blk * 16;
    int* outp = out + (size_t)img*HWP;
    for (int task = t; task < fN * 9; task += 256){
        int s = sF[task / 9];
        int o = task % 9;
        int y = (s >> 9) + (o / 3) - 1;
        int xx = (s & 511) + (o % 3) - 1;
        if (y < row0 || y >= row0 + 16 || xx < 0 || xx >= WW) continue;
        bool conf = false;
        for (int j = 0; j < bN; j++){
            int sb2 = sB[j];
            int dy = y - (sb2 >> 9); if (dy < 0) dy = -dy;
            int dx = xx - (sb2 & 511); if (dx < 0) dx = -dx;
            if (dy <= 1 && dx <= 1){ conf = true; break; }
        }
        if (!conf) outp[y * WW + xx] = 1;
    }
    for (int task = t; task < bN * 9; task += 256){
        int s = sB[task / 9];
        int o = task % 9;
        int y = (s >> 9) + (o / 3) - 1;
        int xx = (s & 511) + (o % 3) - 1;
        if (y < row0 || y >= row0 + 16 || xx < 0 || xx >= WW) continue;
        bool conf = false;
        for (int j = 0; j < fN; j++){
            int sf2 = sF[j];
            int dy = y - (sf2 >> 9); if (dy < 0) dy = -dy;
            int dx = xx - (sf2 & 511); if (dx < 0) dx = -dx;
            if (dy <= 1 && dx <= 1){ conf = true; break; }
        }
        if (!conf) outp[y * WW + xx] = 0;
    }
}

extern "C" void kernel_launch(void* const* d_in, const int* in_sizes, int n_in,
                              void* d_out, int out_size, void* d_ws, size_t ws_size,
                              hipStream_t stream)
{
    (void)in_sizes; (void)n_in; (void)out_size; (void)ws_size;
    const float* x   = (const float*)d_in[0];
    const float* thr = (const float*)d_in[1];
    const float* ufg = (const float*)d_in[2];
    const float* ubg = (const float*)d_in[3];
    int* out = (int*)d_out;
    char* ws = (char*)d_ws;

    size_t off = 0;
    auto carve = [&](size_t bytes) -> char* {
        char* ptr = ws + off;
        off = (off + bytes + 255) & ~(size_t)255;
        return ptr;
    };
    u32* shf      = (u32*)carve((size_t)BB*NBS*4);
    u32* shb      = (u32*)carve((size_t)BB*NBS*4);
    u32* cnts     = (u32*)carve((size_t)4*BB*4);
    size_t zero_bytes = off;
    u32* roiE     = (u32*)carve((size_t)BB*WPI*4);
    int* prm      = (int*)carve((size_t)BB*PN*4);
    uint2* scandF = (uint2*)carve((size_t)BB*CAND_CAP*8);
    uint2* scandB = (uint2*)carve((size_t)BB*CAND_CAP*8);
    uint2* selF   = (uint2*)carve((size_t)BB*SEL_CAP*8);
    uint2* selB   = (uint2*)carve((size_t)BB*SEL_CAP*8);
    int* gSeedF   = (int*)carve((size_t)BB*SEL_CAP*4);
    int* gSeedB   = (int*)carve((size_t)BB*SEL_CAP*4);
    int* gnF      = (int*)carve((size_t)BB*4);
    int* gnB      = (int*)carve((size_t)BB*4);
    u32* cntSelF = cnts, *cntScF = cnts + BB, *cntSelB = cnts + 2*BB, *cntScB = cnts + 3*BB;

    hipMemsetAsync(ws, 0, zero_bytes, stream);

    k_roi     <<<64,   TA,  0, stream>>>(x, thr, roiE, prm);
    k_shist   <<<2048, 256, 0, stream>>>(x, roiE, ufg, ubg, prm, shf, shb);
    k_bound2  <<<64,   256, 0, stream>>>(shf, shb, prm);
    k_collect2<<<2048, 256, 0, stream>>>(x, roiE, ufg, ubg, prm,
                                         selF, cntSelF, scandF, cntScF,
                                         selB, cntSelB, scandB, cntScB);
    k_seeds   <<<64,   256, 0, stream>>>(selF, cntSelF, scandF, cntScF,
                                         selB, cntSelB, scandB, cntScB, prm,
                                         gSeedF, gnF, gSeedB, gnB);
    k_paint   <<<2048, 256, 0, stream>>>(gSeedF, gnF, gSeedB, gnB, out);
}